// Round 6
// baseline (386.754 us; speedup 1.0000x reference)
//
#include <hip/hip_runtime.h>
#include <math.h>

// Problem constants (fixed by the reference's setup_inputs)
#define EPS_F 0.1f
#define L2E   1.44269504088896340736f   // log2(e)
#define SCALE (L2E / EPS_F)             // convert nats/EPS -> log2 units
constexpr int S = 16, H = 128, K = 64, B = 256, ITERS = 20;
#define INV_S 0.0625f                   // a = 1/S, the row marginal weight

typedef float vf2 __attribute__((ext_vector_type(2)));

// ---------- small device helpers ----------
template <int CTRL>
__device__ __forceinline__ float dpp_mov(float x, float old) {
  return __int_as_float(__builtin_amdgcn_update_dpp(
      __float_as_int(old), __float_as_int(x), CTRL, 0xF, 0xF, false));
}
// Full-wave (64-lane) sum on the VALU pipe via DPP; result valid in lane 63.
__device__ __forceinline__ float wave_sum63(float x) {
  x += dpp_mov<0x111>(x, 0.f);   // row_shr:1
  x += dpp_mov<0x112>(x, 0.f);   // row_shr:2
  x += dpp_mov<0x114>(x, 0.f);   // row_shr:4
  x += dpp_mov<0x118>(x, 0.f);   // row_shr:8
  x += dpp_mov<0x142>(x, 0.f);   // row_bcast:15
  x += dpp_mov<0x143>(x, 0.f);   // row_bcast:31
  return x;
}
__device__ __forceinline__ float rl63(float x) {
  return __int_as_float(__builtin_amdgcn_readlane(__float_as_int(x), 63));
}
__device__ __forceinline__ float rfl(float x) {
  return __int_as_float(__builtin_amdgcn_readfirstlane(__float_as_int(x)));
}
#if __has_builtin(__builtin_amdgcn_exp2f)
__device__ __forceinline__ float ex2(float x) { return __builtin_amdgcn_exp2f(x); }
#else
__device__ __forceinline__ float ex2(float x) { return exp2f(x); }
#endif
#if __has_builtin(__builtin_amdgcn_logf)
__device__ __forceinline__ float lg2(float x) { return __builtin_amdgcn_logf(x); }
#else
__device__ __forceinline__ float lg2(float x) { return log2f(x); }
#endif
#if __has_builtin(__builtin_amdgcn_rcpf)
__device__ __forceinline__ float rcpa(float x) { return __builtin_amdgcn_rcpf(x); }
#else
__device__ __forceinline__ float rcpa(float x) { return 1.0f / x; }
#endif
__device__ __forceinline__ vf2 pkfma(vf2 a, vf2 b, vf2 c) {
#if __has_builtin(__builtin_elementwise_fma)
  return __builtin_elementwise_fma(a, b, c);   // -> v_pk_fma_f32 on gfx950
#else
  vf2 r; r.x = fmaf(a.x, b.x, c.x); r.y = fmaf(a.y, b.y, c.y); return r;
#endif
}

// ---------- prep: transpose+scale codebook, y^2, log-softmax prior ----------
__global__ void prep_kernel(const float* __restrict__ cb, const float* __restrict__ lp,
                            float* __restrict__ Z, float* __restrict__ y2s,
                            float* __restrict__ B2, float* __restrict__ prior) {
  const int t = threadIdx.x;  // one block of 256
  // Z stored as float4 chunks: Z4[c][k] = 2*SCALE*y[k][4c..4c+3], c in [0,32)
  for (int i = t; i < K * H / 4; i += 256) {
    const int c = i >> 6;
    const int k = i & 63;
    const float* p = cb + k * H + c * 4;
    float4 v;
    v.x = p[0] * (2.f * SCALE);
    v.y = p[1] * (2.f * SCALE);
    v.z = p[2] * (2.f * SCALE);
    v.w = p[3] * (2.f * SCALE);
    reinterpret_cast<float4*>(Z)[i] = v;
  }
  if (t < K) {
    const int k = t;
    float acc = 0.f;
    for (int d = 0; d < H; ++d) { const float v = cb[k * H + d]; acc = fmaf(v, v, acc); }
    y2s[k] = acc * SCALE;
    // log2-softmax of log_codebook_prior
    float m = -__builtin_inff();
    for (int j = 0; j < K; ++j) m = fmaxf(m, lp[j]);
    float s2 = 0.f;
    for (int j = 0; j < K; ++j) s2 += ex2((lp[j] - m) * L2E);
    const float b2 = (lp[k] - m) * L2E - lg2(s2);
    B2[k] = b2;           // log2(prior_k)
    prior[k] = ex2(b2);   // softmax fallback for empty graphs
  }
}

// ---------- main: one wave per node ----------
//
// Hybrid schedule (21 (g,f) pairs total, exactly matching the ref's 20 scan
// steps + 1 extrapolation; histogram from (f21,g21)):
//   pairs 1,2*:   exact log2-domain (g1,f1,g2 exact; f2 via linear u)
//   pairs 3..20:  LINEAR fixed-point in the (F1,Gt2) frame on the cached
//                 plan matrix A1[s][k] = 2^{F1_s+Gt2_k+W_sk}:
//                   u_s  = a / sum_k vb_k A1_sk
//                   vb_k = b_k / sum_s u_s A1_sk
//                 (a=1/S keeps marginal targets consistent -- r1 fix)
//   pair 21 + histogram: EXACT log2 domain, the verified numerical path
//                 (r3's all-linear histogram was 4.3e-4; this path 1.2e-4).
//
// r6: launch_bounds(256,6). r5's (256,8) forced VGPR 52->32 -> heavy scratch
// spills (WRITE_SIZE 5.6->85.6 MB, VALUBusy 49%). Bound 6 gives the allocator
// an ~84-VGPR budget (needs ~56, no spill); natural allocation <=64 VGPRs
// still lets HW schedule 8 blocks/CU (LDS 19.2KB/block allows 8). The bound
// is a floor, not a cap -- worst case 6 blocks/CU, no spills.
//
// Layouts: K-layout = lane k owns column k (A1K[s] regs, g-update in-lane).
//          T-layout = lane (ts=lane>>2, tq=lane&3) owns row ts, k-chunk
//          tq*16..tq*16+15 (t0..t3 regs, f-update in-lane + 2 quad-perm DPP).
// u/vb/F cross layouts via tiny same-wave LDS buffers (broadcast reads, no
// barriers -- waves are independent; same-wave LDS ops execute in order).
__global__ __launch_bounds__(256, 6)
void pool_kernel(const float* __restrict__ nd, const int* __restrict__ bidx,
                 const float* __restrict__ Z, const float* __restrict__ y2s,
                 const float* __restrict__ B2g,
                 float* __restrict__ sums, float* __restrict__ counts, int N) {
  // per-wave region (1200 floats = 4.8KB):
  //   [0,1024)    x half-tile (8 rows x 128), two staging phases; later
  //   [0,1088)    scratch rows (stride 68 floats) -- reuses the x region
  //   [1088,1152) vbuf   [1152,1168) ubuf   [1168,1184) fbuf
  //   [1184,1200) ||x_s||^2
  __shared__ __align__(16) float smem[4][1200];   // 19.2 KB total, 8 blocks/CU
  const int w = threadIdx.x >> 6;
  const int lane = threadIdx.x & 63;
  const int node = blockIdx.x * 4 + w;
  if (node >= N) return;
  float* const sm = smem[w];

  // ---- stage x (two s-halves) + W[s] = (2*x_s.y_k - y_k^2)*SCALE ----
  const float* xp = nd + (size_t)node * (S * H);
  const float4* Z4 = reinterpret_cast<const float4*>(Z);
  const float y2k = y2s[lane];
  vf2 W2[S];
#pragma unroll
  for (int s = 0; s < S; ++s) { W2[s].x = -y2k; W2[s].y = 0.f; }
#pragma unroll
  for (int p = 0; p < 2; ++p) {
    // stage rows s = 8p..8p+7 (coalesced float4; same addresses/order as r4)
#pragma unroll
    for (int c8 = 0; c8 < 4; ++c8) {
      const int off = c8 * 256 + lane * 4;       // covers s_local = 2c8 + (lane>=32)
      const float4 v = *reinterpret_cast<const float4*>(xp + p * 1024 + off);
      *reinterpret_cast<float4*>(&sm[off]) = v;
      float pp = v.x * v.x + v.y * v.y + v.z * v.z + v.w * v.w;
      pp += __shfl_xor(pp, 1);
      pp += __shfl_xor(pp, 2);
      pp += __shfl_xor(pp, 4);
      pp += __shfl_xor(pp, 8);
      pp += __shfl_xor(pp, 16);                  // stays within each 32-lane half
      if ((lane & 31) == 0) sm[1184 + p * 8 + c8 * 2 + (lane >> 5)] = pp;
    }
    // W partial for these 8 rows (c ascending -> same accumulation order as r4)
    for (int c = 0; c < 32; ++c) {
      const float4 z = Z4[c * 64 + lane];        // coalesced, L1-hot
      vf2 zlo; zlo.x = z.x; zlo.y = z.y;
      vf2 zhi; zhi.x = z.z; zhi.y = z.w;
#pragma unroll
      for (int sl = 0; sl < 8; ++sl) {
        const float4 x4 = *reinterpret_cast<const float4*>(&sm[sl * 128 + c * 4]); // LDS bcast
        vf2 xlo; xlo.x = x4.x; xlo.y = x4.y;
        vf2 xhi; xhi.x = x4.z; xhi.y = x4.w;
        W2[p * 8 + sl] = pkfma(xlo, zlo, W2[p * 8 + sl]);
        W2[p * 8 + sl] = pkfma(xhi, zhi, W2[p * 8 + sl]);
      }
    }
  }
  float W[S];
#pragma unroll
  for (int s = 0; s < S; ++s) W[s] = W2[s].x + W2[s].y;

  // ---- F0[s] = -(x2[s]-x2[0])*SCALE (trajectory-preserving shift) ----
  float F0[S];
  {
    const float mu = sm[1184];
#pragma unroll
    for (int s = 0; s < S; ++s) F0[s] = rfl(-(sm[1184 + s] - mu) * SCALE);
  }

  const float B2 = B2g[lane];
  const float bk = ex2(B2);                      // prior_k (bit-identical to prep)
  const int ts = lane >> 2, tq = lane & 3;
  float* const trow = sm + ts * 68 + tq * 16;    // T-layout scratch row chunk

  // ---- g1 exact (in-lane lse over s) ----
  float Gt1;
  {
    float m = -__builtin_inff();
#pragma unroll
    for (int s = 0; s < S; ++s) m = fmaxf(m, F0[s] + W[s]);
    float sum = 0.f;
#pragma unroll
    for (int s = 0; s < S; ++s) sum += ex2(F0[s] + W[s] - m);
    Gt1 = -(m + lg2(sum)) + B2;                  // \tilde G = G + log2 b
  }

  // ---- f1 exact over all 64 k, via scratch transpose (in-lane + quad DPP) ----
#pragma unroll
  for (int s = 0; s < S; ++s) sm[s * 68 + lane] = W[s] + Gt1;
  {
    const float4 a0 = *reinterpret_cast<const float4*>(trow + 0);
    const float4 a1 = *reinterpret_cast<const float4*>(trow + 4);
    const float4 a2 = *reinterpret_cast<const float4*>(trow + 8);
    const float4 a3 = *reinterpret_cast<const float4*>(trow + 12);
    const float NI = -__builtin_inff();
    float m = fmaxf(fmaxf(fmaxf(a0.x, a0.y), fmaxf(a0.z, a0.w)),
                    fmaxf(fmaxf(a1.x, a1.y), fmaxf(a1.z, a1.w)));
    m = fmaxf(m, fmaxf(fmaxf(fmaxf(a2.x, a2.y), fmaxf(a2.z, a2.w)),
                       fmaxf(fmaxf(a3.x, a3.y), fmaxf(a3.z, a3.w))));
    m = fmaxf(m, dpp_mov<0xB1>(m, NI));          // quad_perm xor1
    m = fmaxf(m, dpp_mov<0x4E>(m, NI));          // quad_perm xor2 -> max over 64 k
    float e0 = ex2(a0.x - m) + ex2(a0.y - m) + ex2(a0.z - m) + ex2(a0.w - m);
    float e1 = ex2(a1.x - m) + ex2(a1.y - m) + ex2(a1.z - m) + ex2(a1.w - m);
    float e2 = ex2(a2.x - m) + ex2(a2.y - m) + ex2(a2.z - m) + ex2(a2.w - m);
    float e3 = ex2(a3.x - m) + ex2(a3.y - m) + ex2(a3.z - m) + ex2(a3.w - m);
    float sv = (e0 + e1) + (e2 + e3);
    sv += dpp_mov<0xB1>(sv, 0.f);
    sv += dpp_mov<0x4E>(sv, 0.f);
    const float F1 = -(m + lg2(sv));
    if (tq == 0) sm[1168 + ts] = F1;             // fbuf
  }

  // ---- F1 to K-layout; g2 exact; A1K[s] = 2^{F1_s + Gt2_k + W_sk} ----
  float A1K[S];
  {
    const float4 f0 = *reinterpret_cast<const float4*>(sm + 1168);
    const float4 f1 = *reinterpret_cast<const float4*>(sm + 1172);
    const float4 f2 = *reinterpret_cast<const float4*>(sm + 1176);
    const float4 f3 = *reinterpret_cast<const float4*>(sm + 1180);
    float fw[S];
    fw[0]  = f0.x + W[0];  fw[1]  = f0.y + W[1];  fw[2]  = f0.z + W[2];  fw[3]  = f0.w + W[3];
    fw[4]  = f1.x + W[4];  fw[5]  = f1.y + W[5];  fw[6]  = f1.z + W[6];  fw[7]  = f1.w + W[7];
    fw[8]  = f2.x + W[8];  fw[9]  = f2.y + W[9];  fw[10] = f2.z + W[10]; fw[11] = f2.w + W[11];
    fw[12] = f3.x + W[12]; fw[13] = f3.y + W[13]; fw[14] = f3.z + W[14]; fw[15] = f3.w + W[15];
    float m = -__builtin_inff();
#pragma unroll
    for (int s = 0; s < S; ++s) m = fmaxf(m, fw[s]);
    float sum = 0.f;
#pragma unroll
    for (int s = 0; s < S; ++s) sum += ex2(fw[s] - m);
    const float Gt2 = -(m + lg2(sum)) + B2;
#pragma unroll
    for (int s = 0; s < S; ++s) A1K[s] = ex2(fw[s] + Gt2);  // entries <= b_k
  }

  // ---- transpose A1 through scratch -> T-layout regs t0..t3 ----
#pragma unroll
  for (int s = 0; s < S; ++s) sm[s * 68 + lane] = A1K[s];
  const float4 t0 = *reinterpret_cast<const float4*>(trow + 0);
  const float4 t1 = *reinterpret_cast<const float4*>(trow + 4);
  const float4 t2 = *reinterpret_cast<const float4*>(trow + 8);
  const float4 t3 = *reinterpret_cast<const float4*>(trow + 12);

  // ---- f2 (vb = 1): u = a/rowsum(A1) ----
  float u_prev = INV_S;                          // u(f1) = a (frame identity)
  bool active;
  {
    float r0 = ((t0.x + t0.y) + (t0.z + t0.w)) + ((t1.x + t1.y) + (t1.z + t1.w));
    float r1 = ((t2.x + t2.y) + (t2.z + t2.w)) + ((t3.x + t3.y) + (t3.z + t3.w));
    float rs = r0 + r1;
    rs += dpp_mov<0xB1>(rs, 0.f);
    rs += dpp_mov<0x4E>(rs, 0.f);                // rowsum over all 64 k
    const float u = INV_S * rcpa(fmaxf(rs, 1e-30f));
    if (tq == 0) sm[1152 + ts] = u;              // ubuf
    active = __any(fabsf(u - u_prev) > 6.9e-7f * u) != 0;  // 1e-6 log2 units
    u_prev = u;
  }

  // ---- linear (g,f) pairs t = 3..20; early exit at fixpoint ----
  if (active) for (int it = 3; it <= ITERS; ++it) {
    // g: colsum in K-layout (4 independent fma chains), vb = b/colsum
    const float4 u0 = *reinterpret_cast<const float4*>(sm + 1152);
    const float4 u1 = *reinterpret_cast<const float4*>(sm + 1156);
    const float4 u2 = *reinterpret_cast<const float4*>(sm + 1160);
    const float4 u3 = *reinterpret_cast<const float4*>(sm + 1164);
    float p0 = A1K[0] * u0.x; p0 = fmaf(A1K[4], u1.x, p0); p0 = fmaf(A1K[8],  u2.x, p0); p0 = fmaf(A1K[12], u3.x, p0);
    float p1 = A1K[1] * u0.y; p1 = fmaf(A1K[5], u1.y, p1); p1 = fmaf(A1K[9],  u2.y, p1); p1 = fmaf(A1K[13], u3.y, p1);
    float p2 = A1K[2] * u0.z; p2 = fmaf(A1K[6], u1.z, p2); p2 = fmaf(A1K[10], u2.z, p2); p2 = fmaf(A1K[14], u3.z, p2);
    float p3 = A1K[3] * u0.w; p3 = fmaf(A1K[7], u1.w, p3); p3 = fmaf(A1K[11], u2.w, p3); p3 = fmaf(A1K[15], u3.w, p3);
    const float cs = (p0 + p1) + (p2 + p3);
    sm[1088 + lane] = bk * rcpa(fmaxf(cs, 1e-30f));   // vbuf

    // f: rowsum in T-layout (broadcast vb chunk + in-lane fma + 2 quad DPP)
    const float* vrow = sm + 1088 + tq * 16;
    const float4 v0 = *reinterpret_cast<const float4*>(vrow + 0);
    const float4 v1 = *reinterpret_cast<const float4*>(vrow + 4);
    const float4 v2 = *reinterpret_cast<const float4*>(vrow + 8);
    const float4 v3 = *reinterpret_cast<const float4*>(vrow + 12);
    float r0 = t0.x * v0.x; r0 = fmaf(t1.x, v1.x, r0); r0 = fmaf(t2.x, v2.x, r0); r0 = fmaf(t3.x, v3.x, r0);
    float r1 = t0.y * v0.y; r1 = fmaf(t1.y, v1.y, r1); r1 = fmaf(t2.y, v2.y, r1); r1 = fmaf(t3.y, v3.y, r1);
    float r2 = t0.z * v0.z; r2 = fmaf(t1.z, v1.z, r2); r2 = fmaf(t2.z, v2.z, r2); r2 = fmaf(t3.z, v3.z, r2);
    float r3 = t0.w * v0.w; r3 = fmaf(t1.w, v1.w, r3); r3 = fmaf(t2.w, v2.w, r3); r3 = fmaf(t3.w, v3.w, r3);
    float rs = (r0 + r1) + (r2 + r3);
    rs += dpp_mov<0xB1>(rs, 0.f);
    rs += dpp_mov<0x4E>(rs, 0.f);
    const float u = INV_S * rcpa(fmaxf(rs, 1e-30f));
    if (tq == 0) sm[1152 + ts] = u;
    const bool moved = fabsf(u - u_prev) > 6.9e-7f * u;
    u_prev = u;
    if (!__any(moved)) break;                    // remaining ref iters are identity
  }

  // ==== exact log2-domain pair 21 + histogram (old verified path) ====

  // ---- convert: F20[s] = F1[s] + lg2(16*u[s])  (wave-uniform) ----
  float Fc[S];
  {
    const float4 f0 = *reinterpret_cast<const float4*>(sm + 1168);  // fbuf = F1
    const float4 f1 = *reinterpret_cast<const float4*>(sm + 1172);
    const float4 f2 = *reinterpret_cast<const float4*>(sm + 1176);
    const float4 f3 = *reinterpret_cast<const float4*>(sm + 1180);
    const float4 u0 = *reinterpret_cast<const float4*>(sm + 1152);  // ubuf = final u
    const float4 u1 = *reinterpret_cast<const float4*>(sm + 1156);
    const float4 u2 = *reinterpret_cast<const float4*>(sm + 1160);
    const float4 u3 = *reinterpret_cast<const float4*>(sm + 1164);
    Fc[0]  = f0.x + lg2(16.f * u0.x); Fc[1]  = f0.y + lg2(16.f * u0.y);
    Fc[2]  = f0.z + lg2(16.f * u0.z); Fc[3]  = f0.w + lg2(16.f * u0.w);
    Fc[4]  = f1.x + lg2(16.f * u1.x); Fc[5]  = f1.y + lg2(16.f * u1.y);
    Fc[6]  = f1.z + lg2(16.f * u1.z); Fc[7]  = f1.w + lg2(16.f * u1.w);
    Fc[8]  = f2.x + lg2(16.f * u2.x); Fc[9]  = f2.y + lg2(16.f * u2.y);
    Fc[10] = f2.z + lg2(16.f * u2.z); Fc[11] = f2.w + lg2(16.f * u2.w);
    Fc[12] = f3.x + lg2(16.f * u3.x); Fc[13] = f3.y + lg2(16.f * u3.y);
    Fc[14] = f3.z + lg2(16.f * u3.z); Fc[15] = f3.w + lg2(16.f * u3.w);
  }

  // ---- g21 exact (in-lane lse over s) ----
  float Gt;
  {
    float m = -__builtin_inff();
#pragma unroll
    for (int s = 0; s < S; ++s) m = fmaxf(m, Fc[s] + W[s]);
    float sum = 0.f;
#pragma unroll
    for (int s = 0; s < S; ++s) sum += ex2(Fc[s] + W[s] - m);
    Gt = -(m + lg2(sum)) + B2;
  }

  // ---- f21 exact over all 64 k (T-layout; scratch A1 rows are dead now) ----
#pragma unroll
  for (int s = 0; s < S; ++s) sm[s * 68 + lane] = W[s] + Gt;
  {
    const float4 a0 = *reinterpret_cast<const float4*>(trow + 0);
    const float4 a1 = *reinterpret_cast<const float4*>(trow + 4);
    const float4 a2 = *reinterpret_cast<const float4*>(trow + 8);
    const float4 a3 = *reinterpret_cast<const float4*>(trow + 12);
    const float NI = -__builtin_inff();
    float m = fmaxf(fmaxf(fmaxf(a0.x, a0.y), fmaxf(a0.z, a0.w)),
                    fmaxf(fmaxf(a1.x, a1.y), fmaxf(a1.z, a1.w)));
    m = fmaxf(m, fmaxf(fmaxf(fmaxf(a2.x, a2.y), fmaxf(a2.z, a2.w)),
                       fmaxf(fmaxf(a3.x, a3.y), fmaxf(a3.z, a3.w))));
    m = fmaxf(m, dpp_mov<0xB1>(m, NI));
    m = fmaxf(m, dpp_mov<0x4E>(m, NI));
    float e0 = ex2(a0.x - m) + ex2(a0.y - m) + ex2(a0.z - m) + ex2(a0.w - m);
    float e1 = ex2(a1.x - m) + ex2(a1.y - m) + ex2(a1.z - m) + ex2(a1.w - m);
    float e2 = ex2(a2.x - m) + ex2(a2.y - m) + ex2(a2.z - m) + ex2(a2.w - m);
    float e3 = ex2(a3.x - m) + ex2(a3.y - m) + ex2(a3.z - m) + ex2(a3.w - m);
    float sv = (e0 + e1) + (e2 + e3);
    sv += dpp_mov<0xB1>(sv, 0.f);
    sv += dpp_mov<0x4E>(sv, 0.f);
    const float F21 = -(m + lg2(sv));
    if (tq == 0) sm[1168 + ts] = F21;            // fbuf := F21
  }

  // ---- histogram h_k = sum_s 2^{F21_s + Gt_k + W_sk}, normalize, pool ----
  {
    const float4 f0 = *reinterpret_cast<const float4*>(sm + 1168);
    const float4 f1 = *reinterpret_cast<const float4*>(sm + 1172);
    const float4 f2 = *reinterpret_cast<const float4*>(sm + 1176);
    const float4 f3 = *reinterpret_cast<const float4*>(sm + 1180);
    float Ff[S];
    Ff[0]  = f0.x; Ff[1]  = f0.y; Ff[2]  = f0.z; Ff[3]  = f0.w;
    Ff[4]  = f1.x; Ff[5]  = f1.y; Ff[6]  = f1.z; Ff[7]  = f1.w;
    Ff[8]  = f2.x; Ff[9]  = f2.y; Ff[10] = f2.z; Ff[11] = f2.w;
    Ff[12] = f3.x; Ff[13] = f3.y; Ff[14] = f3.z; Ff[15] = f3.w;
    float h = 0.f;
#pragma unroll
    for (int s = 0; s < S; ++s) h += ex2(Ff[s] + Gt + W[s]);   // args <= ~0 (f21-normalized)
    const float tot = rl63(wave_sum63(h));
    const float hn = h / (tot + 1e-12f);
    const int b = bidx[node];
    atomicAdd(&sums[b * K + lane], hn);
    if (lane == 0) atomicAdd(&counts[b], 1.f);
  }
}

// ---------- finish: segment mean with prior fallback ----------
__global__ void finish_kernel(const float* __restrict__ sums, const float* __restrict__ counts,
                              const float* __restrict__ prior, float* __restrict__ out) {
  const int t = blockIdx.x * 256 + threadIdx.x;
  if (t >= B * K) return;
  const int b = t >> 6;
  const int k = t & 63;
  const float c = counts[b];
  out[t] = (c > 0.f) ? sums[t] / fmaxf(c, 1.f) : prior[k];
}

extern "C" void kernel_launch(void* const* d_in, const int* in_sizes, int n_in,
                              void* d_out, int out_size, void* d_ws, size_t ws_size,
                              hipStream_t stream) {
  const float* nd  = (const float*)d_in[0];   // [N,S,H] f32
  const int*   bx  = (const int*)d_in[1];     // [N] i32
  const float* cb  = (const float*)d_in[2];   // [K,H] f32
  const float* lp  = (const float*)d_in[3];   // [K] f32
  const int N = in_sizes[1];

  float* ws     = (float*)d_ws;
  float* sums   = ws;                  // B*K
  float* counts = ws + B * K;          // B
  float* Z      = counts + B;          // K*H (transposed+scaled codebook)
  float* y2s    = Z + K * H;           // K
  float* B2     = y2s + K;             // K
  float* prior  = B2 + K;              // K

  hipMemsetAsync(ws, 0, (size_t)(B * K + B) * sizeof(float), stream);
  prep_kernel<<<1, 256, 0, stream>>>(cb, lp, Z, y2s, B2, prior);
  pool_kernel<<<(N + 3) / 4, 256, 0, stream>>>(nd, bx, Z, y2s, B2, sums, counts, N);
  finish_kernel<<<(B * K + 255) / 256, 256, 0, stream>>>(sums, counts, prior, (float*)d_out);
}

// Round 7
// 359.423 us; speedup vs baseline: 1.0760x; 1.0760x over previous
//
#include <hip/hip_runtime.h>
#include <math.h>

// Problem constants (fixed by the reference's setup_inputs)
#define EPS_F 0.1f
#define L2E   1.44269504088896340736f   // log2(e)
#define SCALE (L2E / EPS_F)             // convert nats/EPS -> log2 units
constexpr int S = 16, H = 128, K = 64, B = 256, ITERS = 20;
#define INV_S 0.0625f                   // a = 1/S, the row marginal weight

typedef float vf2 __attribute__((ext_vector_type(2)));

// ---------- small device helpers ----------
template <int CTRL>
__device__ __forceinline__ float dpp_mov(float x, float old) {
  return __int_as_float(__builtin_amdgcn_update_dpp(
      __float_as_int(old), __float_as_int(x), CTRL, 0xF, 0xF, false));
}
// Full-wave (64-lane) sum on the VALU pipe via DPP; result valid in lane 63.
__device__ __forceinline__ float wave_sum63(float x) {
  x += dpp_mov<0x111>(x, 0.f);   // row_shr:1
  x += dpp_mov<0x112>(x, 0.f);   // row_shr:2
  x += dpp_mov<0x114>(x, 0.f);   // row_shr:4
  x += dpp_mov<0x118>(x, 0.f);   // row_shr:8
  x += dpp_mov<0x142>(x, 0.f);   // row_bcast:15
  x += dpp_mov<0x143>(x, 0.f);   // row_bcast:31
  return x;
}
__device__ __forceinline__ float rl63(float x) {
  return __int_as_float(__builtin_amdgcn_readlane(__float_as_int(x), 63));
}
__device__ __forceinline__ float rfl(float x) {
  return __int_as_float(__builtin_amdgcn_readfirstlane(__float_as_int(x)));
}
#if __has_builtin(__builtin_amdgcn_exp2f)
__device__ __forceinline__ float ex2(float x) { return __builtin_amdgcn_exp2f(x); }
#else
__device__ __forceinline__ float ex2(float x) { return exp2f(x); }
#endif
#if __has_builtin(__builtin_amdgcn_logf)
__device__ __forceinline__ float lg2(float x) { return __builtin_amdgcn_logf(x); }
#else
__device__ __forceinline__ float lg2(float x) { return log2f(x); }
#endif
#if __has_builtin(__builtin_amdgcn_rcpf)
__device__ __forceinline__ float rcpa(float x) { return __builtin_amdgcn_rcpf(x); }
#else
__device__ __forceinline__ float rcpa(float x) { return 1.0f / x; }
#endif
__device__ __forceinline__ vf2 pkfma(vf2 a, vf2 b, vf2 c) {
#if __has_builtin(__builtin_elementwise_fma)
  return __builtin_elementwise_fma(a, b, c);   // -> v_pk_fma_f32 on gfx950
#else
  vf2 r; r.x = fmaf(a.x, b.x, c.x); r.y = fmaf(a.y, b.y, c.y); return r;
#endif
}

// ---------- prep: transpose+scale codebook, y^2, log-softmax prior ----------
__global__ void prep_kernel(const float* __restrict__ cb, const float* __restrict__ lp,
                            float* __restrict__ Z, float* __restrict__ y2s,
                            float* __restrict__ B2, float* __restrict__ prior) {
  const int t = threadIdx.x;  // one block of 256
  // Z stored as float4 chunks: Z4[c][k] = 2*SCALE*y[k][4c..4c+3], c in [0,32)
  for (int i = t; i < K * H / 4; i += 256) {
    const int c = i >> 6;
    const int k = i & 63;
    const float* p = cb + k * H + c * 4;
    float4 v;
    v.x = p[0] * (2.f * SCALE);
    v.y = p[1] * (2.f * SCALE);
    v.z = p[2] * (2.f * SCALE);
    v.w = p[3] * (2.f * SCALE);
    reinterpret_cast<float4*>(Z)[i] = v;
  }
  if (t < K) {
    const int k = t;
    float acc = 0.f;
    for (int d = 0; d < H; ++d) { const float v = cb[k * H + d]; acc = fmaf(v, v, acc); }
    y2s[k] = acc * SCALE;
    // log2-softmax of log_codebook_prior
    float m = -__builtin_inff();
    for (int j = 0; j < K; ++j) m = fmaxf(m, lp[j]);
    float s2 = 0.f;
    for (int j = 0; j < K; ++j) s2 += ex2((lp[j] - m) * L2E);
    const float b2 = (lp[k] - m) * L2E - lg2(s2);
    B2[k] = b2;           // log2(prior_k)
    prior[k] = ex2(b2);   // softmax fallback for empty graphs
  }
}

// ---------- main: one wave per node ----------
//
// Hybrid schedule (21 (g,f) pairs total, exactly matching the ref's 20 scan
// steps + 1 extrapolation; histogram from (f21,g21)):
//   pairs 1,2*:   exact log2-domain (g1,f1,g2 exact; f2 via linear u)
//   pairs 3..20:  LINEAR fixed-point in the (F1,Gt2) frame on the cached
//                 plan matrix A1[s][k] = 2^{F1_s+Gt2_k+W_sk}:
//                   u_s  = a / sum_k vb_k A1_sk
//                   vb_k = b_k / sum_s u_s A1_sk
//                 (a=1/S keeps marginal targets consistent -- r1 fix)
//   pair 21 + histogram: EXACT log2 domain, the verified numerical path
//                 (r3's all-linear histogram was 4.3e-4; this path 1.2e-4).
//
// r7: launch_bounds back to (256,4) -- the NATURAL allocation point.
// Occupancy sweep evidence: (256,4)+33KB LDS = 52 VGPR/79% VALUBusy/204us;
// (256,8) = 32 VGPR + scratch spills/49%/213us; (256,6) = 40 VGPR, no spills
// but ILP destroyed (serialized W loop)/44%/230us. This kernel wants ILP
// over TLP: keep the 52-VGPR schedule. With r5's LDS shrink (19,456 B/block
// -> 8 blocks/CU) the runtime occupancy is min(LDS:8, VGPR: 512/52->8) = 8
// blocks/CU WITHOUT constraining the allocator -- bound 4 is just a floor.
//
// Layouts: K-layout = lane k owns column k (A1K[s] regs, g-update in-lane).
//          T-layout = lane (ts=lane>>2, tq=lane&3) owns row ts, k-chunk
//          tq*16..tq*16+15 (t0..t3 regs, f-update in-lane + 2 quad-perm DPP).
// u/vb/F cross layouts via tiny same-wave LDS buffers (broadcast reads, no
// barriers -- waves are independent; same-wave LDS ops execute in order).
__global__ __launch_bounds__(256, 4)
void pool_kernel(const float* __restrict__ nd, const int* __restrict__ bidx,
                 const float* __restrict__ Z, const float* __restrict__ y2s,
                 const float* __restrict__ B2g,
                 float* __restrict__ sums, float* __restrict__ counts, int N) {
  // per-wave region (1200 floats = 4.8KB):
  //   [0,1024)    x half-tile (8 rows x 128), two staging phases; later
  //   [0,1088)    scratch rows (stride 68 floats) -- reuses the x region
  //   [1088,1152) vbuf   [1152,1168) ubuf   [1168,1184) fbuf
  //   [1184,1200) ||x_s||^2
  __shared__ __align__(16) float smem[4][1200];   // 19.2 KB total, 8 blocks/CU
  const int w = threadIdx.x >> 6;
  const int lane = threadIdx.x & 63;
  const int node = blockIdx.x * 4 + w;
  if (node >= N) return;
  float* const sm = smem[w];

  // ---- stage x (two s-halves) + W[s] = (2*x_s.y_k - y_k^2)*SCALE ----
  const float* xp = nd + (size_t)node * (S * H);
  const float4* Z4 = reinterpret_cast<const float4*>(Z);
  const float y2k = y2s[lane];
  vf2 W2[S];
#pragma unroll
  for (int s = 0; s < S; ++s) { W2[s].x = -y2k; W2[s].y = 0.f; }
#pragma unroll
  for (int p = 0; p < 2; ++p) {
    // stage rows s = 8p..8p+7 (coalesced float4; same addresses/order as r4)
#pragma unroll
    for (int c8 = 0; c8 < 4; ++c8) {
      const int off = c8 * 256 + lane * 4;       // covers s_local = 2c8 + (lane>=32)
      const float4 v = *reinterpret_cast<const float4*>(xp + p * 1024 + off);
      *reinterpret_cast<float4*>(&sm[off]) = v;
      float pp = v.x * v.x + v.y * v.y + v.z * v.z + v.w * v.w;
      pp += __shfl_xor(pp, 1);
      pp += __shfl_xor(pp, 2);
      pp += __shfl_xor(pp, 4);
      pp += __shfl_xor(pp, 8);
      pp += __shfl_xor(pp, 16);                  // stays within each 32-lane half
      if ((lane & 31) == 0) sm[1184 + p * 8 + c8 * 2 + (lane >> 5)] = pp;
    }
    // W partial for these 8 rows (c ascending -> same accumulation order as r4)
    for (int c = 0; c < 32; ++c) {
      const float4 z = Z4[c * 64 + lane];        // coalesced, L1-hot
      vf2 zlo; zlo.x = z.x; zlo.y = z.y;
      vf2 zhi; zhi.x = z.z; zhi.y = z.w;
#pragma unroll
      for (int sl = 0; sl < 8; ++sl) {
        const float4 x4 = *reinterpret_cast<const float4*>(&sm[sl * 128 + c * 4]); // LDS bcast
        vf2 xlo; xlo.x = x4.x; xlo.y = x4.y;
        vf2 xhi; xhi.x = x4.z; xhi.y = x4.w;
        W2[p * 8 + sl] = pkfma(xlo, zlo, W2[p * 8 + sl]);
        W2[p * 8 + sl] = pkfma(xhi, zhi, W2[p * 8 + sl]);
      }
    }
  }
  float W[S];
#pragma unroll
  for (int s = 0; s < S; ++s) W[s] = W2[s].x + W2[s].y;

  // ---- F0[s] = -(x2[s]-x2[0])*SCALE (trajectory-preserving shift) ----
  float F0[S];
  {
    const float mu = sm[1184];
#pragma unroll
    for (int s = 0; s < S; ++s) F0[s] = rfl(-(sm[1184 + s] - mu) * SCALE);
  }

  const float B2 = B2g[lane];
  const float bk = ex2(B2);                      // prior_k (bit-identical to prep)
  const int ts = lane >> 2, tq = lane & 3;
  float* const trow = sm + ts * 68 + tq * 16;    // T-layout scratch row chunk

  // ---- g1 exact (in-lane lse over s) ----
  float Gt1;
  {
    float m = -__builtin_inff();
#pragma unroll
    for (int s = 0; s < S; ++s) m = fmaxf(m, F0[s] + W[s]);
    float sum = 0.f;
#pragma unroll
    for (int s = 0; s < S; ++s) sum += ex2(F0[s] + W[s] - m);
    Gt1 = -(m + lg2(sum)) + B2;                  // \tilde G = G + log2 b
  }

  // ---- f1 exact over all 64 k, via scratch transpose (in-lane + quad DPP) ----
#pragma unroll
  for (int s = 0; s < S; ++s) sm[s * 68 + lane] = W[s] + Gt1;
  {
    const float4 a0 = *reinterpret_cast<const float4*>(trow + 0);
    const float4 a1 = *reinterpret_cast<const float4*>(trow + 4);
    const float4 a2 = *reinterpret_cast<const float4*>(trow + 8);
    const float4 a3 = *reinterpret_cast<const float4*>(trow + 12);
    const float NI = -__builtin_inff();
    float m = fmaxf(fmaxf(fmaxf(a0.x, a0.y), fmaxf(a0.z, a0.w)),
                    fmaxf(fmaxf(a1.x, a1.y), fmaxf(a1.z, a1.w)));
    m = fmaxf(m, fmaxf(fmaxf(fmaxf(a2.x, a2.y), fmaxf(a2.z, a2.w)),
                       fmaxf(fmaxf(a3.x, a3.y), fmaxf(a3.z, a3.w))));
    m = fmaxf(m, dpp_mov<0xB1>(m, NI));          // quad_perm xor1
    m = fmaxf(m, dpp_mov<0x4E>(m, NI));          // quad_perm xor2 -> max over 64 k
    float e0 = ex2(a0.x - m) + ex2(a0.y - m) + ex2(a0.z - m) + ex2(a0.w - m);
    float e1 = ex2(a1.x - m) + ex2(a1.y - m) + ex2(a1.z - m) + ex2(a1.w - m);
    float e2 = ex2(a2.x - m) + ex2(a2.y - m) + ex2(a2.z - m) + ex2(a2.w - m);
    float e3 = ex2(a3.x - m) + ex2(a3.y - m) + ex2(a3.z - m) + ex2(a3.w - m);
    float sv = (e0 + e1) + (e2 + e3);
    sv += dpp_mov<0xB1>(sv, 0.f);
    sv += dpp_mov<0x4E>(sv, 0.f);
    const float F1 = -(m + lg2(sv));
    if (tq == 0) sm[1168 + ts] = F1;             // fbuf
  }

  // ---- F1 to K-layout; g2 exact; A1K[s] = 2^{F1_s + Gt2_k + W_sk} ----
  float A1K[S];
  {
    const float4 f0 = *reinterpret_cast<const float4*>(sm + 1168);
    const float4 f1 = *reinterpret_cast<const float4*>(sm + 1172);
    const float4 f2 = *reinterpret_cast<const float4*>(sm + 1176);
    const float4 f3 = *reinterpret_cast<const float4*>(sm + 1180);
    float fw[S];
    fw[0]  = f0.x + W[0];  fw[1]  = f0.y + W[1];  fw[2]  = f0.z + W[2];  fw[3]  = f0.w + W[3];
    fw[4]  = f1.x + W[4];  fw[5]  = f1.y + W[5];  fw[6]  = f1.z + W[6];  fw[7]  = f1.w + W[7];
    fw[8]  = f2.x + W[8];  fw[9]  = f2.y + W[9];  fw[10] = f2.z + W[10]; fw[11] = f2.w + W[11];
    fw[12] = f3.x + W[12]; fw[13] = f3.y + W[13]; fw[14] = f3.z + W[14]; fw[15] = f3.w + W[15];
    float m = -__builtin_inff();
#pragma unroll
    for (int s = 0; s < S; ++s) m = fmaxf(m, fw[s]);
    float sum = 0.f;
#pragma unroll
    for (int s = 0; s < S; ++s) sum += ex2(fw[s] - m);
    const float Gt2 = -(m + lg2(sum)) + B2;
#pragma unroll
    for (int s = 0; s < S; ++s) A1K[s] = ex2(fw[s] + Gt2);  // entries <= b_k
  }

  // ---- transpose A1 through scratch -> T-layout regs t0..t3 ----
#pragma unroll
  for (int s = 0; s < S; ++s) sm[s * 68 + lane] = A1K[s];
  const float4 t0 = *reinterpret_cast<const float4*>(trow + 0);
  const float4 t1 = *reinterpret_cast<const float4*>(trow + 4);
  const float4 t2 = *reinterpret_cast<const float4*>(trow + 8);
  const float4 t3 = *reinterpret_cast<const float4*>(trow + 12);

  // ---- f2 (vb = 1): u = a/rowsum(A1) ----
  float u_prev = INV_S;                          // u(f1) = a (frame identity)
  bool active;
  {
    float r0 = ((t0.x + t0.y) + (t0.z + t0.w)) + ((t1.x + t1.y) + (t1.z + t1.w));
    float r1 = ((t2.x + t2.y) + (t2.z + t2.w)) + ((t3.x + t3.y) + (t3.z + t3.w));
    float rs = r0 + r1;
    rs += dpp_mov<0xB1>(rs, 0.f);
    rs += dpp_mov<0x4E>(rs, 0.f);                // rowsum over all 64 k
    const float u = INV_S * rcpa(fmaxf(rs, 1e-30f));
    if (tq == 0) sm[1152 + ts] = u;              // ubuf
    active = __any(fabsf(u - u_prev) > 6.9e-7f * u) != 0;  // 1e-6 log2 units
    u_prev = u;
  }

  // ---- linear (g,f) pairs t = 3..20; early exit at fixpoint ----
  if (active) for (int it = 3; it <= ITERS; ++it) {
    // g: colsum in K-layout (4 independent fma chains), vb = b/colsum
    const float4 u0 = *reinterpret_cast<const float4*>(sm + 1152);
    const float4 u1 = *reinterpret_cast<const float4*>(sm + 1156);
    const float4 u2 = *reinterpret_cast<const float4*>(sm + 1160);
    const float4 u3 = *reinterpret_cast<const float4*>(sm + 1164);
    float p0 = A1K[0] * u0.x; p0 = fmaf(A1K[4], u1.x, p0); p0 = fmaf(A1K[8],  u2.x, p0); p0 = fmaf(A1K[12], u3.x, p0);
    float p1 = A1K[1] * u0.y; p1 = fmaf(A1K[5], u1.y, p1); p1 = fmaf(A1K[9],  u2.y, p1); p1 = fmaf(A1K[13], u3.y, p1);
    float p2 = A1K[2] * u0.z; p2 = fmaf(A1K[6], u1.z, p2); p2 = fmaf(A1K[10], u2.z, p2); p2 = fmaf(A1K[14], u3.z, p2);
    float p3 = A1K[3] * u0.w; p3 = fmaf(A1K[7], u1.w, p3); p3 = fmaf(A1K[11], u2.w, p3); p3 = fmaf(A1K[15], u3.w, p3);
    const float cs = (p0 + p1) + (p2 + p3);
    sm[1088 + lane] = bk * rcpa(fmaxf(cs, 1e-30f));   // vbuf

    // f: rowsum in T-layout (broadcast vb chunk + in-lane fma + 2 quad DPP)
    const float* vrow = sm + 1088 + tq * 16;
    const float4 v0 = *reinterpret_cast<const float4*>(vrow + 0);
    const float4 v1 = *reinterpret_cast<const float4*>(vrow + 4);
    const float4 v2 = *reinterpret_cast<const float4*>(vrow + 8);
    const float4 v3 = *reinterpret_cast<const float4*>(vrow + 12);
    float r0 = t0.x * v0.x; r0 = fmaf(t1.x, v1.x, r0); r0 = fmaf(t2.x, v2.x, r0); r0 = fmaf(t3.x, v3.x, r0);
    float r1 = t0.y * v0.y; r1 = fmaf(t1.y, v1.y, r1); r1 = fmaf(t2.y, v2.y, r1); r1 = fmaf(t3.y, v3.y, r1);
    float r2 = t0.z * v0.z; r2 = fmaf(t1.z, v1.z, r2); r2 = fmaf(t2.z, v2.z, r2); r2 = fmaf(t3.z, v3.z, r2);
    float r3 = t0.w * v0.w; r3 = fmaf(t1.w, v1.w, r3); r3 = fmaf(t2.w, v2.w, r3); r3 = fmaf(t3.w, v3.w, r3);
    float rs = (r0 + r1) + (r2 + r3);
    rs += dpp_mov<0xB1>(rs, 0.f);
    rs += dpp_mov<0x4E>(rs, 0.f);
    const float u = INV_S * rcpa(fmaxf(rs, 1e-30f));
    if (tq == 0) sm[1152 + ts] = u;
    const bool moved = fabsf(u - u_prev) > 6.9e-7f * u;
    u_prev = u;
    if (!__any(moved)) break;                    // remaining ref iters are identity
  }

  // ==== exact log2-domain pair 21 + histogram (old verified path) ====

  // ---- convert: F20[s] = F1[s] + lg2(16*u[s])  (wave-uniform) ----
  float Fc[S];
  {
    const float4 f0 = *reinterpret_cast<const float4*>(sm + 1168);  // fbuf = F1
    const float4 f1 = *reinterpret_cast<const float4*>(sm + 1172);
    const float4 f2 = *reinterpret_cast<const float4*>(sm + 1176);
    const float4 f3 = *reinterpret_cast<const float4*>(sm + 1180);
    const float4 u0 = *reinterpret_cast<const float4*>(sm + 1152);  // ubuf = final u
    const float4 u1 = *reinterpret_cast<const float4*>(sm + 1156);
    const float4 u2 = *reinterpret_cast<const float4*>(sm + 1160);
    const float4 u3 = *reinterpret_cast<const float4*>(sm + 1164);
    Fc[0]  = f0.x + lg2(16.f * u0.x); Fc[1]  = f0.y + lg2(16.f * u0.y);
    Fc[2]  = f0.z + lg2(16.f * u0.z); Fc[3]  = f0.w + lg2(16.f * u0.w);
    Fc[4]  = f1.x + lg2(16.f * u1.x); Fc[5]  = f1.y + lg2(16.f * u1.y);
    Fc[6]  = f1.z + lg2(16.f * u1.z); Fc[7]  = f1.w + lg2(16.f * u1.w);
    Fc[8]  = f2.x + lg2(16.f * u2.x); Fc[9]  = f2.y + lg2(16.f * u2.y);
    Fc[10] = f2.z + lg2(16.f * u2.z); Fc[11] = f2.w + lg2(16.f * u2.w);
    Fc[12] = f3.x + lg2(16.f * u3.x); Fc[13] = f3.y + lg2(16.f * u3.y);
    Fc[14] = f3.z + lg2(16.f * u3.z); Fc[15] = f3.w + lg2(16.f * u3.w);
  }

  // ---- g21 exact (in-lane lse over s) ----
  float Gt;
  {
    float m = -__builtin_inff();
#pragma unroll
    for (int s = 0; s < S; ++s) m = fmaxf(m, Fc[s] + W[s]);
    float sum = 0.f;
#pragma unroll
    for (int s = 0; s < S; ++s) sum += ex2(Fc[s] + W[s] - m);
    Gt = -(m + lg2(sum)) + B2;
  }

  // ---- f21 exact over all 64 k (T-layout; scratch A1 rows are dead now) ----
#pragma unroll
  for (int s = 0; s < S; ++s) sm[s * 68 + lane] = W[s] + Gt;
  {
    const float4 a0 = *reinterpret_cast<const float4*>(trow + 0);
    const float4 a1 = *reinterpret_cast<const float4*>(trow + 4);
    const float4 a2 = *reinterpret_cast<const float4*>(trow + 8);
    const float4 a3 = *reinterpret_cast<const float4*>(trow + 12);
    const float NI = -__builtin_inff();
    float m = fmaxf(fmaxf(fmaxf(a0.x, a0.y), fmaxf(a0.z, a0.w)),
                    fmaxf(fmaxf(a1.x, a1.y), fmaxf(a1.z, a1.w)));
    m = fmaxf(m, fmaxf(fmaxf(fmaxf(a2.x, a2.y), fmaxf(a2.z, a2.w)),
                       fmaxf(fmaxf(a3.x, a3.y), fmaxf(a3.z, a3.w))));
    m = fmaxf(m, dpp_mov<0xB1>(m, NI));
    m = fmaxf(m, dpp_mov<0x4E>(m, NI));
    float e0 = ex2(a0.x - m) + ex2(a0.y - m) + ex2(a0.z - m) + ex2(a0.w - m);
    float e1 = ex2(a1.x - m) + ex2(a1.y - m) + ex2(a1.z - m) + ex2(a1.w - m);
    float e2 = ex2(a2.x - m) + ex2(a2.y - m) + ex2(a2.z - m) + ex2(a2.w - m);
    float e3 = ex2(a3.x - m) + ex2(a3.y - m) + ex2(a3.z - m) + ex2(a3.w - m);
    float sv = (e0 + e1) + (e2 + e3);
    sv += dpp_mov<0xB1>(sv, 0.f);
    sv += dpp_mov<0x4E>(sv, 0.f);
    const float F21 = -(m + lg2(sv));
    if (tq == 0) sm[1168 + ts] = F21;            // fbuf := F21
  }

  // ---- histogram h_k = sum_s 2^{F21_s + Gt_k + W_sk}, normalize, pool ----
  {
    const float4 f0 = *reinterpret_cast<const float4*>(sm + 1168);
    const float4 f1 = *reinterpret_cast<const float4*>(sm + 1172);
    const float4 f2 = *reinterpret_cast<const float4*>(sm + 1176);
    const float4 f3 = *reinterpret_cast<const float4*>(sm + 1180);
    float Ff[S];
    Ff[0]  = f0.x; Ff[1]  = f0.y; Ff[2]  = f0.z; Ff[3]  = f0.w;
    Ff[4]  = f1.x; Ff[5]  = f1.y; Ff[6]  = f1.z; Ff[7]  = f1.w;
    Ff[8]  = f2.x; Ff[9]  = f2.y; Ff[10] = f2.z; Ff[11] = f2.w;
    Ff[12] = f3.x; Ff[13] = f3.y; Ff[14] = f3.z; Ff[15] = f3.w;
    float h = 0.f;
#pragma unroll
    for (int s = 0; s < S; ++s) h += ex2(Ff[s] + Gt + W[s]);   // args <= ~0 (f21-normalized)
    const float tot = rl63(wave_sum63(h));
    const float hn = h / (tot + 1e-12f);
    const int b = bidx[node];
    atomicAdd(&sums[b * K + lane], hn);
    if (lane == 0) atomicAdd(&counts[b], 1.f);
  }
}

// ---------- finish: segment mean with prior fallback ----------
__global__ void finish_kernel(const float* __restrict__ sums, const float* __restrict__ counts,
                              const float* __restrict__ prior, float* __restrict__ out) {
  const int t = blockIdx.x * 256 + threadIdx.x;
  if (t >= B * K) return;
  const int b = t >> 6;
  const int k = t & 63;
  const float c = counts[b];
  out[t] = (c > 0.f) ? sums[t] / fmaxf(c, 1.f) : prior[k];
}

extern "C" void kernel_launch(void* const* d_in, const int* in_sizes, int n_in,
                              void* d_out, int out_size, void* d_ws, size_t ws_size,
                              hipStream_t stream) {
  const float* nd  = (const float*)d_in[0];   // [N,S,H] f32
  const int*   bx  = (const int*)d_in[1];     // [N] i32
  const float* cb  = (const float*)d_in[2];   // [K,H] f32
  const float* lp  = (const float*)d_in[3];   // [K] f32
  const int N = in_sizes[1];

  float* ws     = (float*)d_ws;
  float* sums   = ws;                  // B*K
  float* counts = ws + B * K;          // B
  float* Z      = counts + B;          // K*H (transposed+scaled codebook)
  float* y2s    = Z + K * H;           // K
  float* B2     = y2s + K;             // K
  float* prior  = B2 + K;              // K

  hipMemsetAsync(ws, 0, (size_t)(B * K + B) * sizeof(float), stream);
  prep_kernel<<<1, 256, 0, stream>>>(cb, lp, Z, y2s, B2, prior);
  pool_kernel<<<(N + 3) / 4, 256, 0, stream>>>(nd, bx, Z, y2s, B2, sums, counts, N);
  finish_kernel<<<(B * K + 255) / 256, 256, 0, stream>>>(sums, counts, prior, (float*)d_out);
}